// Round 2
// baseline (701.785 us; speedup 1.0000x reference)
//
#include <hip/hip_runtime.h>

// Correlation / cost-volume (kernel_size=1, stride=1, max_disp=4).
// out[b, dy*9+dx, y, x] = (1/C) * sum_c in1[b,c,y,x] * in2[b,c,y+dy-4,x+dx-4]
// B=8 C=192 H=W=128, fp32. No fp32 MFMA on CDNA4 -> vector-ALU kernel.
//
// R1 structure: 3-wave blocks (one dy per wave, dy-triple per block),
// register-prefetch software pipeline for the in2->LDS staging, LDS row
// stride padded 24->28 dwords (period-8 bank pattern -> 2-way, free).

constexpr int MAXD = 4;
constexpr int WIN  = 2 * MAXD + 1;   // 9
constexpr int Bn = 8, Cn = 192, Hn = 128, Wn = 128;
constexpr int HW = Hn * Wn;

constexpr int XT = 16;               // x tile per block
constexpr int YT = 16;               // y tile per block
constexpr int XR = 4;                // x pixels per thread
constexpr int W2  = XT + 2 * MAXD;   // 24 data dwords per row
constexpr int W2P = 28;              // padded LDS row stride (16B-aligned, 2-way banks)
constexpr int H2  = YT + 2 * MAXD;   // 24
constexpr int CC  = 8;               // channels staged per barrier interval
constexpr int DYG = 3;               // dy values per block (one per wave)
constexpr int NTH = (XT / XR) * YT * DYG;        // 192 threads = 3 waves
constexpr int CHUNKS = CC * H2 * (W2 / 4);       // 1152 16B chunks
constexpr int CPT = CHUNKS / NTH;                // 6 chunks per thread

__global__ __launch_bounds__(NTH, 4)
void corr_kernel(const float* __restrict__ in1,
                 const float* __restrict__ in2,
                 float* __restrict__ out)
{
    __shared__ float s2[CC * H2 * W2P];   // 21,504 B

    const int tid = threadIdx.x;
    const int tx  = tid & 3;           // 0..3  (x group)
    const int ty  = (tid >> 2) & 15;   // 0..15 (y)
    const int w   = tid >> 6;          // 0..2  (wave id within block)

    int bx = blockIdx.x;
    const int dyg = bx % 3;            // dy-triple index
    bx /= 3;
    const int x0 = bx * XT;
    const int y0 = blockIdx.y * YT;
    const int b  = blockIdx.z;
    const int dy = dyg * DYG + w;      // 0..8

    const int x = x0 + tx * XR;
    const int y = y0 + ty;

    const float* in2b = in2 + ((size_t)b * Cn) * HW;
    const float* in1p = in1 + ((size_t)b * Cn) * HW + y * Wn + x;

    // ---- per-thread staging descriptors (invariant across channel loop) ----
    const float* gp[CPT];
    int ldsOff[CPT];
    unsigned allmask = 0;              // 4 valid-bits per chunk, bit 1<<(4j+e)
    #pragma unroll
    for (int j = 0; j < CPT; ++j) {
        int chunk = tid + j * NTH;         // 0..1151
        int k   = chunk % 6;               // 16B chunk within row
        int row = (chunk / 6) % H2;        // 0..23
        int c   = chunk / (6 * H2);        // 0..7
        int gy  = y0 - MAXD + row;
        int gxf = x0 - MAXD + k * 4;
        ldsOff[j] = (c * H2 + row) * W2P + k * 4;
        bool rowOk = (gy >= 0 && gy < Hn);
        unsigned m = 0;
        if (rowOk) {
            #pragma unroll
            for (int e = 0; e < 4; ++e)
                if (gxf + e >= 0 && gxf + e < Wn) m |= (1u << e);
        }
        allmask |= (m << (4 * j));
        gp[j] = rowOk ? (in2b + (size_t)c * HW + gy * Wn + gxf) : in2b;
    }

    float acc[WIN][XR];
    #pragma unroll
    for (int dx = 0; dx < WIN; ++dx)
        #pragma unroll
        for (int i = 0; i < XR; ++i) acc[dx][i] = 0.f;

    float4 pf[CPT];

    auto loadPF = [&](int c0) {
        #pragma unroll
        for (int j = 0; j < CPT; ++j) {
            unsigned m = (allmask >> (4 * j)) & 0xFu;
            const float* rp = gp[j] + (size_t)c0 * HW;
            float4 v;
            if (m == 0xFu) {
                v = *(const float4*)rp;
            } else {
                v.x = v.y = v.z = v.w = 0.f;
                if (m & 1u) v.x = rp[0];
                if (m & 2u) v.y = rp[1];
                if (m & 4u) v.z = rp[2];
                if (m & 8u) v.w = rp[3];
            }
            pf[j] = v;
        }
    };

    loadPF(0);

    for (int c0 = 0; c0 < Cn; c0 += CC) {
        __syncthreads();                   // previous interval's readers done
        #pragma unroll
        for (int j = 0; j < CPT; ++j)
            *(float4*)&s2[ldsOff[j]] = pf[j];
        __syncthreads();

        if (c0 + CC < Cn) loadPF(c0 + CC); // prefetch next interval (hidden)

        // compute 8 channels, two half-batches of 4 (caps live in1 regs)
        #pragma unroll
        for (int h = 0; h < 2; ++h) {
            float4 a1v[4];
            #pragma unroll
            for (int q = 0; q < 4; ++q)
                a1v[q] = *(const float4*)(in1p + (size_t)(c0 + h * 4 + q) * HW);
            #pragma unroll
            for (int q = 0; q < 4; ++q) {
                const int cc = h * 4 + q;
                const float* rowp = &s2[(cc * H2 + ty + dy) * W2P + tx * XR];
                float f[12];
                *(float4*)&f[0] = *(const float4*)(rowp);
                *(float4*)&f[4] = *(const float4*)(rowp + 4);
                *(float4*)&f[8] = *(const float4*)(rowp + 8);
                float4 a1 = a1v[q];
                #pragma unroll
                for (int dx = 0; dx < WIN; ++dx) {
                    acc[dx][0] += a1.x * f[dx + 0];
                    acc[dx][1] += a1.y * f[dx + 1];
                    acc[dx][2] += a1.z * f[dx + 2];
                    acc[dx][3] += a1.w * f[dx + 3];
                }
            }
        }
    }

    const float scale = 1.0f / (float)Cn;
    #pragma unroll
    for (int dx = 0; dx < WIN; ++dx) {
        int d = dy * WIN + dx;
        float4 v = { acc[dx][0] * scale, acc[dx][1] * scale,
                     acc[dx][2] * scale, acc[dx][3] * scale };
        *(float4*)(out + (((size_t)b * (WIN * WIN) + d) * Hn + y) * Wn + x) = v;
    }
}

extern "C" void kernel_launch(void* const* d_in, const int* in_sizes, int n_in,
                              void* d_out, int out_size, void* d_ws, size_t ws_size,
                              hipStream_t stream) {
    const float* in1 = (const float*)d_in[0];
    const float* in2 = (const float*)d_in[1];
    float* out = (float*)d_out;
    dim3 grid((Wn / XT) * 3, Hn / YT, Bn);
    corr_kernel<<<grid, NTH, 0, stream>>>(in1, in2, out);
}

// Round 3
// 404.551 us; speedup vs baseline: 1.7347x; 1.7347x over previous
//
#include <hip/hip_runtime.h>

// Correlation / cost-volume (kernel_size=1, stride=1, max_disp=4).
// out[b, dy*9+dx, y, x] = (1/C) * sum_c in1[b,c,y,x] * in2[b,c,y+dy-4,x+dx-4]
// B=8 C=192 H=W=128, fp32. No fp32 MFMA on CDNA4 -> vector-ALU kernel.
//
// R2: R1 structure (3-wave blocks, dy per wave, register-prefetch pipeline,
// LDS stride 28) with the spill bug fixed: __launch_bounds__(192,2) (R1's
// (192,4) capped VGPRs at 64 -> massive scratch spill, 673MB WRITE_SIZE),
// and 32-bit global offsets instead of 64-bit pointers.

constexpr int MAXD = 4;
constexpr int WIN  = 2 * MAXD + 1;   // 9
constexpr int Bn = 8, Cn = 192, Hn = 128, Wn = 128;
constexpr int HW = Hn * Wn;

constexpr int XT = 16;               // x tile per block
constexpr int YT = 16;               // y tile per block
constexpr int XR = 4;                // x pixels per thread
constexpr int W2  = XT + 2 * MAXD;   // 24 data dwords per row
constexpr int W2P = 28;              // padded LDS row stride (16B-aligned, 2-way banks)
constexpr int H2  = YT + 2 * MAXD;   // 24
constexpr int CC  = 8;               // channels staged per barrier interval
constexpr int DYG = 3;               // dy values per block (one per wave)
constexpr int NTH = (XT / XR) * YT * DYG;        // 192 threads = 3 waves
constexpr int CHUNKS = CC * H2 * (W2 / 4);       // 1152 16B chunks
constexpr int CPT = CHUNKS / NTH;                // 6 chunks per thread

__global__ __launch_bounds__(NTH, 2)
void corr_kernel(const float* __restrict__ in1,
                 const float* __restrict__ in2,
                 float* __restrict__ out)
{
    __shared__ float s2[CC * H2 * W2P];   // 21,504 B

    const int tid = threadIdx.x;
    const int tx  = tid & 3;           // 0..3  (x group)
    const int ty  = (tid >> 2) & 15;   // 0..15 (y)
    const int w   = tid >> 6;          // 0..2  (wave id within block)

    int bx = blockIdx.x;
    const int dyg = bx % 3;            // dy-triple index
    bx /= 3;
    const int x0 = bx * XT;
    const int y0 = blockIdx.y * YT;
    const int b  = blockIdx.z;
    const int dy = dyg * DYG + w;      // 0..8

    const int x = x0 + tx * XR;
    const int y = y0 + ty;

    const float* in2b = in2 + ((size_t)b * Cn) * HW;
    const float* in1c = in1 + ((size_t)b * Cn) * HW + y * Wn + x;

    // ---- per-thread staging descriptors (invariant across channel loop) ----
    int goff[CPT];                     // element offset from in2b (channel 0 of interval)
    int ldsOff[CPT];
    unsigned allmask = 0;              // 4 valid-bits per chunk, bit 1<<(4j+e)
    #pragma unroll
    for (int j = 0; j < CPT; ++j) {
        int chunk = tid + j * NTH;         // 0..1151
        int k   = chunk % 6;               // 16B chunk within row
        int row = (chunk / 6) % H2;        // 0..23
        int c   = chunk / (6 * H2);        // 0..7
        int gy  = y0 - MAXD + row;
        int gxf = x0 - MAXD + k * 4;
        ldsOff[j] = (c * H2 + row) * W2P + k * 4;
        bool rowOk = (gy >= 0 && gy < Hn);
        unsigned m = 0;
        if (rowOk) {
            #pragma unroll
            for (int e = 0; e < 4; ++e)
                if (gxf + e >= 0 && gxf + e < Wn) m |= (1u << e);
        }
        allmask |= (m << (4 * j));
        goff[j] = rowOk ? (c * HW + gy * Wn + gxf) : 0;
    }

    float acc[WIN][XR];
    #pragma unroll
    for (int dx = 0; dx < WIN; ++dx)
        #pragma unroll
        for (int i = 0; i < XR; ++i) acc[dx][i] = 0.f;

    float4 pf[CPT];

    auto loadPF = [&](int c0) {
        const float* base = in2b + (size_t)c0 * HW;
        #pragma unroll
        for (int j = 0; j < CPT; ++j) {
            unsigned m = (allmask >> (4 * j)) & 0xFu;
            const float* rp = base + goff[j];
            float4 v;
            if (m == 0xFu) {
                v = *(const float4*)rp;
            } else {
                v.x = v.y = v.z = v.w = 0.f;
                if (m & 1u) v.x = rp[0];
                if (m & 2u) v.y = rp[1];
                if (m & 4u) v.z = rp[2];
                if (m & 8u) v.w = rp[3];
            }
            pf[j] = v;
        }
    };

    loadPF(0);

    for (int c0 = 0; c0 < Cn; c0 += CC) {
        __syncthreads();                   // previous interval's readers done
        #pragma unroll
        for (int j = 0; j < CPT; ++j)
            *(float4*)&s2[ldsOff[j]] = pf[j];
        __syncthreads();

        if (c0 + CC < Cn) loadPF(c0 + CC); // prefetch next interval (hidden)

        // compute 8 channels, two half-batches of 4 (caps live in1 regs)
        #pragma unroll
        for (int h = 0; h < 2; ++h) {
            float4 a1v[4];
            #pragma unroll
            for (int q = 0; q < 4; ++q)
                a1v[q] = *(const float4*)(in1c + (size_t)(h * 4 + q) * HW);
            #pragma unroll
            for (int q = 0; q < 4; ++q) {
                const int cc = h * 4 + q;
                const float* rowp = &s2[(cc * H2 + ty + dy) * W2P + tx * XR];
                float f[12];
                *(float4*)&f[0] = *(const float4*)(rowp);
                *(float4*)&f[4] = *(const float4*)(rowp + 4);
                *(float4*)&f[8] = *(const float4*)(rowp + 8);
                float4 a1 = a1v[q];
                #pragma unroll
                for (int dx = 0; dx < WIN; ++dx) {
                    acc[dx][0] += a1.x * f[dx + 0];
                    acc[dx][1] += a1.y * f[dx + 1];
                    acc[dx][2] += a1.z * f[dx + 2];
                    acc[dx][3] += a1.w * f[dx + 3];
                }
            }
        }
        in1c += (size_t)CC * HW;
    }

    const float scale = 1.0f / (float)Cn;
    #pragma unroll
    for (int dx = 0; dx < WIN; ++dx) {
        int d = dy * WIN + dx;
        float4 v = { acc[dx][0] * scale, acc[dx][1] * scale,
                     acc[dx][2] * scale, acc[dx][3] * scale };
        *(float4*)(out + (((size_t)b * (WIN * WIN) + d) * Hn + y) * Wn + x) = v;
    }
}

extern "C" void kernel_launch(void* const* d_in, const int* in_sizes, int n_in,
                              void* d_out, int out_size, void* d_ws, size_t ws_size,
                              hipStream_t stream) {
    const float* in1 = (const float*)d_in[0];
    const float* in2 = (const float*)d_in[1];
    float* out = (float*)d_out;
    dim3 grid((Wn / XT) * 3, Hn / YT, Bn);
    corr_kernel<<<grid, NTH, 0, stream>>>(in1, in2, out);
}

// Round 4
// 353.419 us; speedup vs baseline: 1.9857x; 1.1447x over previous
//
#include <hip/hip_runtime.h>

// Correlation / cost-volume (kernel_size=1, stride=1, max_disp=4).
// out[b, dy*9+dx, y, x] = (1/C) * sum_c in1[b,c,y,x] * in2[b,c,y+dy-4,x+dx-4]
// B=8 C=192 H=W=128, fp32. No fp32 MFMA -> vector-ALU kernel.
//
// R3: (a) in2 staged in LDS as bf16 (in1/acc stay fp32; LDS pipe was 2x
// oversubscribed vs VALU since 4 SIMDs share one LDS pipe), row stride 40
// bf16 = 20 dwords -> uniform 4-access/bank (structural min, conflict-free);
// (b) in1 loads for the whole interval issued up front (one latency stall
// per interval, covered by other waves); (c) XCD-swizzled 1D grid so the 3
// dyg sibling blocks of a tile share an XCD L2 (kills 3x HBM re-fetch);
// (d) plain __launch_bounds__(192) — 2nd arg caps VGPR at 512/(3*arg)
// (R1: arg=4 -> 64 VGPR -> catastrophic spill).

constexpr int MAXD = 4;
constexpr int WIN  = 2 * MAXD + 1;   // 9
constexpr int Bn = 8, Cn = 192, Hn = 128, Wn = 128;
constexpr int HW = Hn * Wn;

constexpr int XT = 16;               // x tile per block
constexpr int YT = 16;               // y tile per block
constexpr int XR = 4;                // x pixels per thread
constexpr int W2  = XT + 2 * MAXD;   // 24 data elements per row
constexpr int W2S = 40;              // LDS row stride in bf16 elems (80 B = 20 dwords)
constexpr int H2  = YT + 2 * MAXD;   // 24
constexpr int CC  = 8;               // channels staged per barrier interval
constexpr int DYG = 3;               // dy values per block (one per wave)
constexpr int NTH = (XT / XR) * YT * DYG;        // 192 threads = 3 waves
constexpr int CHUNKS = CC * H2 * (W2 / 4);       // 1152 4-elem chunks
constexpr int CPT = CHUNKS / NTH;                // 6 chunks per thread

__device__ __forceinline__ unsigned short f2bf(float x) {
    unsigned u = __builtin_bit_cast(unsigned, x);
    u += 0x7FFFu + ((u >> 16) & 1u);         // RNE (inputs are finite normals)
    return (unsigned short)(u >> 16);
}
__device__ __forceinline__ float bf2f(unsigned short h) {
    return __builtin_bit_cast(float, ((unsigned)h) << 16);
}

__global__ __launch_bounds__(NTH)
void corr_kernel(const float* __restrict__ in1,
                 const float* __restrict__ in2,
                 float* __restrict__ out)
{
    __shared__ unsigned short s2[CC * H2 * W2S];   // 15,360 B

    const int tid = threadIdx.x;
    const int tx  = tid & 3;           // 0..3  (x group)
    const int ty  = (tid >> 2) & 15;   // 0..15 (y)
    const int w   = tid >> 6;          // 0..2  (wave id within block)

    // XCD swizzle: supergroup of 24 ids = 8 tiles x 3 dyg, dyg stride 8
    // -> the 3 sibling blocks of a tile have ids 8 apart (same XCD under
    // round-robin dispatch) and are dispatched within ~2 rounds.
    const int lin = blockIdx.x;
    const int sg  = lin / 24;
    const int r   = lin - sg * 24;
    const int dyg = r >> 3;            // 0..2
    const int tile = sg * 8 + (r & 7); // 0..511
    const int x0 = (tile & 7) * XT;
    const int y0 = ((tile >> 3) & 7) * YT;
    const int b  = tile >> 6;
    const int dy = dyg * DYG + w;      // 0..8

    const int x = x0 + tx * XR;
    const int y = y0 + ty;

    const float* in2b = in2 + ((size_t)b * Cn) * HW;
    const float* in1c = in1 + ((size_t)b * Cn) * HW + y * Wn + x;

    // ---- per-thread staging descriptors (invariant across channel loop) ----
    int goff[CPT];                     // element offset from in2b (interval ch 0)
    int ldsOff[CPT];                   // element offset in s2
    unsigned allmask = 0;              // 4 valid-bits per chunk
    #pragma unroll
    for (int j = 0; j < CPT; ++j) {
        int chunk = tid + j * NTH;         // 0..1151
        int k   = chunk % 6;               // 4-elem chunk within row
        int row = (chunk / 6) % H2;        // 0..23
        int c   = chunk / (6 * H2);        // 0..7
        int gy  = y0 - MAXD + row;
        int gxf = x0 - MAXD + k * 4;
        ldsOff[j] = (c * H2 + row) * W2S + k * 4;
        bool rowOk = (gy >= 0 && gy < Hn);
        unsigned m = 0;
        if (rowOk) {
            #pragma unroll
            for (int e = 0; e < 4; ++e)
                if (gxf + e >= 0 && gxf + e < Wn) m |= (1u << e);
        }
        allmask |= (m << (4 * j));
        goff[j] = rowOk ? (c * HW + gy * Wn + gxf) : 0;
    }

    float acc[WIN][XR];
    #pragma unroll
    for (int dx = 0; dx < WIN; ++dx)
        #pragma unroll
        for (int i = 0; i < XR; ++i) acc[dx][i] = 0.f;

    ushort4 pf[CPT];                   // bf16 x4 per chunk (12 VGPRs total)

    auto loadPF = [&](int c0) {
        const float* base = in2b + (size_t)c0 * HW;
        #pragma unroll
        for (int j = 0; j < CPT; ++j) {
            unsigned m = (allmask >> (4 * j)) & 0xFu;
            const float* rp = base + goff[j];
            float4 v;
            if (m == 0xFu) {
                v = *(const float4*)rp;
            } else {
                v.x = v.y = v.z = v.w = 0.f;
                if (m & 1u) v.x = rp[0];
                if (m & 2u) v.y = rp[1];
                if (m & 4u) v.z = rp[2];
                if (m & 8u) v.w = rp[3];
            }
            pf[j] = make_ushort4(f2bf(v.x), f2bf(v.y), f2bf(v.z), f2bf(v.w));
        }
    };

    loadPF(0);

    for (int c0 = 0; c0 < Cn; c0 += CC) {
        __syncthreads();                   // previous interval's readers done
        #pragma unroll
        for (int j = 0; j < CPT; ++j)
            *(ushort4*)&s2[ldsOff[j]] = pf[j];
        __syncthreads();

        // issue ALL in1 loads for this interval first (oldest in vmcnt queue),
        // then the in2 prefetch for the next interval.
        float4 a1v[CC];
        #pragma unroll
        for (int q = 0; q < CC; ++q)
            a1v[q] = *(const float4*)(in1c + (size_t)q * HW);

        if (c0 + CC < Cn) loadPF(c0 + CC);

        #pragma unroll
        for (int cc = 0; cc < CC; ++cc) {
            const unsigned short* rowp = &s2[(cc * H2 + ty + dy) * W2S + tx * XR];
            ushort4 h0 = *(const ushort4*)(rowp);       // f[0..3]
            ushort4 h1 = *(const ushort4*)(rowp + 4);   // f[4..7]
            ushort4 h2 = *(const ushort4*)(rowp + 8);   // f[8..11]
            float f[12];
            f[0] = bf2f(h0.x); f[1]  = bf2f(h0.y); f[2]  = bf2f(h0.z); f[3]  = bf2f(h0.w);
            f[4] = bf2f(h1.x); f[5]  = bf2f(h1.y); f[6]  = bf2f(h1.z); f[7]  = bf2f(h1.w);
            f[8] = bf2f(h2.x); f[9]  = bf2f(h2.y); f[10] = bf2f(h2.z); f[11] = bf2f(h2.w);
            float4 a1 = a1v[cc];
            #pragma unroll
            for (int dx = 0; dx < WIN; ++dx) {
                acc[dx][0] += a1.x * f[dx + 0];
                acc[dx][1] += a1.y * f[dx + 1];
                acc[dx][2] += a1.z * f[dx + 2];
                acc[dx][3] += a1.w * f[dx + 3];
            }
        }
        in1c += (size_t)CC * HW;
    }

    const float scale = 1.0f / (float)Cn;
    #pragma unroll
    for (int dx = 0; dx < WIN; ++dx) {
        int d = dy * WIN + dx;
        float4 v = { acc[dx][0] * scale, acc[dx][1] * scale,
                     acc[dx][2] * scale, acc[dx][3] * scale };
        *(float4*)(out + (((size_t)b * (WIN * WIN) + d) * Hn + y) * Wn + x) = v;
    }
}

extern "C" void kernel_launch(void* const* d_in, const int* in_sizes, int n_in,
                              void* d_out, int out_size, void* d_ws, size_t ws_size,
                              hipStream_t stream) {
    const float* in1 = (const float*)d_in[0];
    const float* in2 = (const float*)d_in[1];
    float* out = (float*)d_out;
    dim3 grid((Wn / XT) * (Hn / YT) * Bn * 3);   // 1536 blocks, 1D, swizzled
    corr_kernel<<<grid, NTH, 0, stream>>>(in1, in2, out);
}